// Round 4
// baseline (316.163 us; speedup 1.0000x reference)
//
#include <hip/hip_runtime.h>
#include <math.h>

// B=128, K=64, M=2048, QD=128, AD=128, H=256, C=32
// out: y [0,786432) | type_logits [786432,9175040) | weight_logits [9175040,9437184)

typedef __attribute__((ext_vector_type(8))) short short8;
typedef __attribute__((ext_vector_type(4))) float f32x4;

__device__ __forceinline__ unsigned short bf16_rne(float f){
    union { float f; unsigned u; } v; v.f = f;
    return (unsigned short)((v.u + 0x7FFFu + ((v.u >> 16) & 1u)) >> 16);
}

// exact-erf gelu (A&S 7.1.26, abs err ~1.5e-7) - used in small prep paths
__device__ __forceinline__ float gelu_f(float x){
    float z  = x * 0.70710678118654752f;
    float az = fabsf(z);
    float t  = __builtin_amdgcn_rcpf(1.0f + 0.3275911f * az);
    float p  = t*(0.254829592f + t*(-0.284496736f + t*(1.421413741f + t*(-1.453152027f + t*1.061405429f))));
    float e  = __expf(-az*az);
    float er = copysignf(1.0f - p*e, z);
    return 0.5f * x * (1.0f + er);
}

// tanh-form gelu: x*sigmoid(2*0.7978845608*(x+0.044715 x^3)); error <1e-5 for |x|<0.5
// (our preacts are all O(0.1)); 7 VALU insts, 2 quarter-rate.
__device__ __forceinline__ float gelu_fast(float x){
    float x2 = x*x;
    float p  = fmaf(x2, -0.1029433f, -2.3022082f);   // -(2*0.79788456*log2e)*(1, 0.044715)
    float u  = x*p;
    float e  = __builtin_amdgcn_exp2f(u);
    float r  = __builtin_amdgcn_rcpf(1.0f + e);
    return x*r;
}

// ---------------- fused prep kernel 1 (436 blocks) ----------------
// [0,32) inv | 32 v,s0 | [33,97) w2->bf16 | [97,131) head fold | [131,163) w1q->bf16
// [163,227) query->bf16 | [227,291) gmW2^T | [291,355) gmW3^T | [355,419) w1g^T
// [419,435) gmW1^T | 435 w385
__global__ void k_pre1(const float* __restrict__ g, const float* __restrict__ qW,
                       const float* __restrict__ qb, const float* __restrict__ kW,
                       const float* __restrict__ query, const float* __restrict__ pmW1,
                       const float* __restrict__ pmW2, const float* __restrict__ pmW3,
                       const float* __restrict__ pmb3,
                       const float* __restrict__ gmW1, const float* __restrict__ gmW2,
                       const float* __restrict__ gmW3,
                       const float* __restrict__ tW, const float* __restrict__ tb,
                       const float* __restrict__ wW, const float* __restrict__ wb,
                       const float* __restrict__ cW, const float* __restrict__ cb,
                       float* __restrict__ invg, float* __restrict__ vg, float* __restrict__ s0g,
                       unsigned short* __restrict__ w2b, unsigned short* __restrict__ wheadb,
                       float* __restrict__ bheadg,
                       unsigned short* __restrict__ w1qb, unsigned short* __restrict__ queryb,
                       float* __restrict__ gmW1t, float* __restrict__ gmW2t,
                       float* __restrict__ gmW3t, float* __restrict__ w1gt,
                       float* __restrict__ w385g) {
    const int bid = blockIdx.x, tid = threadIdx.x;
    if (bid < 32) {
        int idx = bid*256 + tid;
        const float* p = g + idx*3;
        invg[idx] = sqrtf(p[0]*p[0] + p[1]*p[1] + p[2]*p[2]);
    } else if (bid == 32) {
        if (tid < 128) {
            float acc = 0.f;
            for (int d = 0; d < 128; ++d) acc += qW[d*128 + tid] * kW[d];
            vg[tid] = acc;
            if (tid == 0) {
                float s = 0.f;
                for (int d = 0; d < 128; ++d) s += qb[d] * kW[d];
                *s0g = s;
            }
        }
    } else if (bid < 97) {
        int o = (bid - 33)*1024 + tid*4;
        float4 x = *(const float4*)&pmW2[o];
        union { unsigned short u[4]; uint2 v; } r;
        r.u[0] = bf16_rne(x.x); r.u[1] = bf16_rne(x.y);
        r.u[2] = bf16_rne(x.z); r.u[3] = bf16_rne(x.w);
        *(uint2*)&w2b[o] = r.v;
    } else if (bid < 131) {
        __shared__ float hw[256];
        int c = bid - 97;
        const float* src = (c < 32) ? (tW + c*256) : ((c == 32) ? wW : cW);
        hw[tid] = src[tid];
        __syncthreads();
        float acc = 0.f;
        for (int j = 0; j < 256; ++j) acc += hw[j] * pmW3[j*256 + tid];
        wheadb[c*256 + tid] = bf16_rne(acc);
        if (tid == 0) {
            float bacc = (c < 32) ? tb[c] : ((c == 32) ? wb[0] : cb[0]);
            for (int j = 0; j < 256; ++j) bacc += hw[j] * pmb3[j];
            bheadg[c] = bacc;
        }
    } else if (bid < 163) {
        int o = (bid - 131)*1024 + tid*4;  // w1qb[n*128+k] = pmW1[n*385+256+k]
        int n = o >> 7, k = o & 127;
        union { unsigned short u[4]; uint2 v; } r;
        #pragma unroll
        for (int i = 0; i < 4; ++i) r.u[i] = bf16_rne(pmW1[n*385 + 256 + k + i]);
        *(uint2*)&w1qb[o] = r.v;
    } else if (bid < 227) {
        int base = (bid - 163)*4096 + tid*4;
        #pragma unroll
        for (int it = 0; it < 4; ++it) {
            int o = base + it*1024;
            float4 x = *(const float4*)&query[o];
            union { unsigned short u[4]; uint2 v; } r;
            r.u[0] = bf16_rne(x.x); r.u[1] = bf16_rne(x.y);
            r.u[2] = bf16_rne(x.z); r.u[3] = bf16_rne(x.w);
            *(uint2*)&queryb[o] = r.v;
        }
    } else if (bid < 291) {
        int o = (bid - 227)*1024 + tid*4;  // gmW2t[i*256+j] = gmW2[j*256+i]
        int i = o >> 8, j = o & 255;
        float4 r = { gmW2[j*256+i], gmW2[(j+1)*256+i], gmW2[(j+2)*256+i], gmW2[(j+3)*256+i] };
        *(float4*)&gmW2t[o] = r;
    } else if (bid < 355) {
        int o = (bid - 291)*1024 + tid*4;
        int i = o >> 8, j = o & 255;
        float4 r = { gmW3[j*256+i], gmW3[(j+1)*256+i], gmW3[(j+2)*256+i], gmW3[(j+3)*256+i] };
        *(float4*)&gmW3t[o] = r;
    } else if (bid < 419) {
        int o = (bid - 355)*1024 + tid*4;  // w1gt[i*256+j] = pmW1[j*385+i]
        int i = o >> 8, j = o & 255;
        float4 r = { pmW1[j*385+i], pmW1[(j+1)*385+i], pmW1[(j+2)*385+i], pmW1[(j+3)*385+i] };
        *(float4*)&w1gt[o] = r;
    } else if (bid < 435) {
        int o = (bid - 419)*1024 + tid*4;  // gmW1t[k*256+j] = gmW1[j*64+k]
        int k = o >> 8, j = o & 255;
        float4 r = { gmW1[j*64+k], gmW1[(j+1)*64+k], gmW1[(j+2)*64+k], gmW1[(j+3)*64+k] };
        *(float4*)&gmW1t[o] = r;
    } else {
        w385g[tid] = pmW1[tid*385 + 384];
    }
}

// ---------------- fused prep kernel 2 (136 blocks) ----------------
// [0,8) a[m] | [8,136) global-MLP + u1 fold (coalesced via transposed weights)
__global__ void k_pre2(const float* __restrict__ query, const float* __restrict__ vg,
                       const float* __restrict__ s0g, const float* __restrict__ invg,
                       const float* __restrict__ gmW1t, const float* __restrict__ gmb1,
                       const float* __restrict__ gmW2t, const float* __restrict__ gmb2,
                       const float* __restrict__ gmW3t, const float* __restrict__ gmb3,
                       const float* __restrict__ w1gt, const float* __restrict__ pmb1,
                       float* __restrict__ ag, float* __restrict__ u1g) {
    const int bid = blockIdx.x, tid = threadIdx.x;
    if (bid < 8) {
        __shared__ float vs[128];
        if (tid < 128) vs[tid] = vg[tid];
        __syncthreads();
        int m = bid*256 + tid;
        const float4* qp = (const float4*)(query + m*128);
        float acc = *s0g;
        #pragma unroll 8
        for (int e4 = 0; e4 < 32; ++e4) {
            float4 q = qp[e4];
            acc += q.x*vs[e4*4] + q.y*vs[e4*4+1] + q.z*vs[e4*4+2] + q.w*vs[e4*4+3];
        }
        ag[m] = acc * 0.08838834764831845f; // 1/sqrt(128)
    } else {
        __shared__ float s_in[64];
        __shared__ float s_h[256];
        __shared__ float s_h2[256];
        int b = bid - 8;
        if (tid < 64) s_in[tid] = invg[b*64 + tid];
        __syncthreads();
        float acc = gmb1[tid];
        #pragma unroll 8
        for (int k = 0; k < 64; ++k) acc += gmW1t[k*256 + tid] * s_in[k];
        s_h[tid] = gelu_f(acc);
        __syncthreads();
        acc = gmb2[tid];
        #pragma unroll 8
        for (int i = 0; i < 256; ++i) acc += gmW2t[i*256 + tid] * s_h[i];
        s_h2[tid] = gelu_f(acc);
        __syncthreads();
        acc = gmb3[tid];
        #pragma unroll 8
        for (int i = 0; i < 256; ++i) acc += gmW3t[i*256 + tid] * s_h2[i];
        __syncthreads();
        s_h[tid] = acc;        // global_s
        __syncthreads();
        float u = pmb1[tid];
        #pragma unroll 8
        for (int i = 0; i < 256; ++i) u += w1gt[i*256 + tid] * s_h[i];
        u1g[b*256 + tid] = u;
    }
}

// ---------------- main fused kernel ----------------
// One block = 64 rows (same b). 4096 blocks x 256 threads.
__global__ __launch_bounds__(256, 4)
void k_main(const float* __restrict__ g,
            const float* __restrict__ invg, const float* __restrict__ ag,
            const float* __restrict__ u1g, const float* __restrict__ w385g,
            const float* __restrict__ pmb2,
            const unsigned short* __restrict__ queryb, const unsigned short* __restrict__ w1qb,
            const unsigned short* __restrict__ w2b, const unsigned short* __restrict__ wheadb,
            const float* __restrict__ bheadg, float* __restrict__ out) {
    // row stride 264 shorts (132 dwords == 4 mod 32 -> 2-way aliasing, free)
    __shared__ __align__(16) unsigned short hb[64*264];  // h1, later h2
    __shared__ float invs[64], gsl[192], u1s[256], w385s[256], pmb2s[256];
    __shared__ float ainv_s[64], y0s[192];

    const int tid = threadIdx.x;
    const int bid = blockIdx.x;
    const int b  = bid >> 5;           // 32 tiles per b
    const int m0 = (bid & 31) << 6;    // 64 rows

    if (tid < 64)  invs[tid] = invg[b*64 + tid];
    if (tid < 192) gsl[tid]  = g[b*192 + tid];
    u1s[tid]   = u1g[b*256 + tid];
    w385s[tid] = w385g[tid];
    pmb2s[tid] = pmb2[tid];
    __syncthreads();

    // ---- phase 1: rank-1 softmax over k; 4 threads per row ----
    {
        const int r = tid >> 2, sub = tid & 3;
        const float am = ag[m0 + r];
        const int kb = sub * 16;
        float mx = -1e30f;
        #pragma unroll
        for (int i = 0; i < 16; ++i) mx = fmaxf(mx, invs[kb + i] * am);
        #pragma unroll
        for (int d = 1; d < 4; d <<= 1) mx = fmaxf(mx, __shfl_xor(mx, d, 64));
        float den = 0.f, ai = 0.f, y0 = 0.f, y1 = 0.f, y2 = 0.f;
        #pragma unroll
        for (int i = 0; i < 16; ++i) {
            const int k = kb + i;
            const float iv = invs[k];
            const float e = __expf(iv * am - mx);
            den += e; ai += e * iv;
            y0 += e * gsl[k*3+0]; y1 += e * gsl[k*3+1]; y2 += e * gsl[k*3+2];
        }
        #pragma unroll
        for (int d = 1; d < 4; d <<= 1) {
            den += __shfl_xor(den, d, 64);
            ai  += __shfl_xor(ai , d, 64);
            y0  += __shfl_xor(y0 , d, 64);
            y1  += __shfl_xor(y1 , d, 64);
            y2  += __shfl_xor(y2 , d, 64);
        }
        if (sub == 0) {
            const float id = 1.0f / den;
            ainv_s[r] = ai * id;
            y0s[r*3+0] = y0*id; y0s[r*3+1] = y1*id; y0s[r*3+2] = y2*id;
        }
    }
    __syncthreads();

    const int w = tid >> 6, lane = tid & 63;
    const int q = lane >> 4, ln = lane & 15;

    // ---- phase 1b: u2 = query @ W1q^T via MFMA (64x256x128), fused epilogue:
    //      h1 = gelu(u2 + u1[b] + ainv*w385) -> bf16 LDS ----
    {
        f32x4 acc[4][4];
        #pragma unroll
        for (int mt = 0; mt < 4; ++mt)
            #pragma unroll
            for (int nt = 0; nt < 4; ++nt) acc[mt][nt] = (f32x4){0.f,0.f,0.f,0.f};
        #pragma unroll
        for (int kk = 0; kk < 4; ++kk) {
            const int kc = kk*32 + q*8;
            short8 afr[4], bfr[4];
            #pragma unroll
            for (int mt = 0; mt < 4; ++mt)
                afr[mt] = *(const short8*)&queryb[(m0 + mt*16 + ln)*128 + kc];
            #pragma unroll
            for (int nt = 0; nt < 4; ++nt)
                bfr[nt] = *(const short8*)&w1qb[(w*64 + nt*16 + ln)*128 + kc];
            #pragma unroll
            for (int mt = 0; mt < 4; ++mt)
                #pragma unroll
                for (int nt = 0; nt < 4; ++nt)
                    acc[mt][nt] = __builtin_amdgcn_mfma_f32_16x16x32_bf16(afr[mt], bfr[nt], acc[mt][nt], 0, 0, 0);
        }
        #pragma unroll
        for (int mt = 0; mt < 4; ++mt) {
            #pragma unroll
            for (int nt = 0; nt < 4; ++nt) {
                const int n = w*64 + nt*16 + ln;
                const float u1v = u1s[n], wv = w385s[n];
                #pragma unroll
                for (int rg = 0; rg < 4; ++rg) {
                    const int r = mt*16 + q*4 + rg;
                    const float x = acc[mt][nt][rg] + u1v + ainv_s[r]*wv;
                    hb[r*264 + n] = bf16_rne(gelu_fast(x));
                }
            }
        }
    }
    __syncthreads();

    // ---- phase 2: h2 = gelu(H1 @ W2^T + b2), 64x256x256 bf16 MFMA ----
    f32x4 acc[4][4];
    #pragma unroll
    for (int mt = 0; mt < 4; ++mt)
        #pragma unroll
        for (int nt = 0; nt < 4; ++nt) acc[mt][nt] = (f32x4){0.f,0.f,0.f,0.f};

    #pragma unroll 2
    for (int kk = 0; kk < 8; ++kk) {
        const int kc = kk*32 + q*8;
        short8 afrag[4], bfrag[4];
        #pragma unroll
        for (int mt = 0; mt < 4; ++mt)
            afrag[mt] = *(const short8*)&hb[(mt*16 + ln)*264 + kc];
        #pragma unroll
        for (int nt = 0; nt < 4; ++nt)
            bfrag[nt] = *(const short8*)&w2b[(w*64 + nt*16 + ln)*256 + kc];
        #pragma unroll
        for (int mt = 0; mt < 4; ++mt)
            #pragma unroll
            for (int nt = 0; nt < 4; ++nt)
                acc[mt][nt] = __builtin_amdgcn_mfma_f32_16x16x32_bf16(afrag[mt], bfrag[nt], acc[mt][nt], 0, 0, 0);
    }
    __syncthreads();

    // h2 = gelu(acc + b2) -> bf16 back into hb
    #pragma unroll
    for (int mt = 0; mt < 4; ++mt) {
        #pragma unroll
        for (int nt = 0; nt < 4; ++nt) {
            const int n = w*64 + nt*16 + ln;
            const float bb = pmb2s[n];
            #pragma unroll
            for (int rg = 0; rg < 4; ++rg) {
                const int r = mt*16 + q*4 + rg;
                hb[r*264 + n] = bf16_rne(gelu_fast(acc[mt][nt][rg] + bb));
            }
        }
    }
    __syncthreads();

    // ---- phase 3: heads: D[c][r] = Whead[c,:] . h2[r,:]; wave w owns rows w*16..+15 ----
    f32x4 accA0 = {0.f,0.f,0.f,0.f}, accA1 = {0.f,0.f,0.f,0.f}, accB = {0.f,0.f,0.f,0.f};
    const int rr = w*16 + ln;
    const int cb2 = (ln < 2) ? (32 + ln) : 33;   // rows >=34 don't exist
    #pragma unroll 2
    for (int kk = 0; kk < 8; ++kk) {
        const int kc = kk*32 + q*8;
        short8 bh = *(const short8*)&hb[rr*264 + kc];
        short8 a0 = *(const short8*)&wheadb[ ln      *256 + kc];
        short8 a1 = *(const short8*)&wheadb[(16 + ln)*256 + kc];
        short8 a2 = *(const short8*)&wheadb[ cb2     *256 + kc];
        accA0 = __builtin_amdgcn_mfma_f32_16x16x32_bf16(a0, bh, accA0, 0, 0, 0);
        accA1 = __builtin_amdgcn_mfma_f32_16x16x32_bf16(a1, bh, accA1, 0, 0, 0);
        accB  = __builtin_amdgcn_mfma_f32_16x16x32_bf16(a2, bh, accB , 0, 0, 0);
    }
    {
        const size_t row = (size_t)b*2048 + m0 + rr;
        const int c0 = q*4;
        f32x4 r0 = accA0 + *(const f32x4*)&bheadg[c0];
        f32x4 r1 = accA1 + *(const f32x4*)&bheadg[16 + c0];
        *(f32x4*)&out[786432 + row*32 + c0]      = r0;
        *(f32x4*)&out[786432 + row*32 + 16 + c0] = r1;
        if (q == 0) {
            out[9175040 + row] = accB[0] + bheadg[32];
            float gv = accB[1] + bheadg[33];
            float gt = 1.0f / (1.0f + __expf(-gv));
            gt = fminf(fmaxf(gt, 0.0f), 1.0f);
            float* yo = out + row*3;
            yo[0] = y0s[rr*3+0] * gt;
            yo[1] = y0s[rr*3+1] * gt;
            yo[2] = y0s[rr*3+2] * gt;
        }
    }
}

// ---------------- launcher ----------------
extern "C" void kernel_launch(void* const* d_in, const int* in_sizes, int n_in,
                              void* d_out, int out_size, void* d_ws, size_t ws_size,
                              hipStream_t stream) {
    const float* g     = (const float*)d_in[0];
    const float* query = (const float*)d_in[1];
    const float* qW    = (const float*)d_in[2];
    const float* qb    = (const float*)d_in[3];
    const float* kW    = (const float*)d_in[4];
    // d_in[5] = kb (cancels in softmax)
    const float* gmW1  = (const float*)d_in[6];
    const float* gmb1  = (const float*)d_in[7];
    const float* gmW2  = (const float*)d_in[8];
    const float* gmb2  = (const float*)d_in[9];
    const float* gmW3  = (const float*)d_in[10];
    const float* gmb3  = (const float*)d_in[11];
    const float* pmW1  = (const float*)d_in[12];
    const float* pmb1  = (const float*)d_in[13];
    const float* pmW2  = (const float*)d_in[14];
    const float* pmb2  = (const float*)d_in[15];
    const float* pmW3  = (const float*)d_in[16];
    const float* pmb3  = (const float*)d_in[17];
    const float* tW    = (const float*)d_in[18];
    const float* tb    = (const float*)d_in[19];
    const float* wW    = (const float*)d_in[20];
    const float* wb    = (const float*)d_in[21];
    const float* cW    = (const float*)d_in[22];
    const float* cb    = (const float*)d_in[23];
    float* out = (float*)d_out;

    // workspace layout (float slots)
    float* ws    = (float*)d_ws;
    float* invg  = ws;                                       // 8192
    float* ag    = ws + 8192;                                // 2048
    float* vg    = ws + 10240;                               // 128
    float* s0g   = ws + 10368;                               // pad -> 10496
    float* u1g   = ws + 10496;                               // 32768 -> 43264
    float* gmW1t = ws + 43264;                               // 16384 -> 59648
    float* gmW2t = ws + 59648;                               // 65536 -> 125184
    float* gmW3t = ws + 125184;                              // 65536 -> 190720
    float* w1gt  = ws + 190720;                              // 65536 -> 256256
    float* w385g = ws + 256256;                              // 256 -> 256512
    float* bheadg= ws + 256512;                              // 64 -> 256576
    unsigned short* w2b    = (unsigned short*)(ws + 256576); // 65536 sh -> 289344
    unsigned short* wheadb = (unsigned short*)(ws + 289344); // 8704 sh -> 293696
    unsigned short* w1qb   = (unsigned short*)(ws + 293696); // 32768 sh -> 310080
    unsigned short* queryb = (unsigned short*)(ws + 310080); // 262144 sh -> 441152

    hipLaunchKernelGGL(k_pre1, dim3(436), dim3(256), 0, stream,
                       g, qW, qb, kW, query, pmW1, pmW2, pmW3, pmb3,
                       gmW1, gmW2, gmW3,
                       tW, tb, wW, wb, cW, cb,
                       invg, vg, s0g, w2b, wheadb, bheadg,
                       w1qb, queryb, gmW1t, gmW2t, gmW3t, w1gt, w385g);
    hipLaunchKernelGGL(k_pre2, dim3(136), dim3(256), 0, stream,
                       query, vg, s0g, invg,
                       gmW1t, gmb1, gmW2t, gmb2, gmW3t, gmb3, w1gt, pmb1,
                       ag, u1g);
    hipLaunchKernelGGL(k_main, dim3(4096), dim3(256), 0, stream,
                       g, invg, ag, u1g, w385g, pmb2,
                       queryb, w1qb, w2b, wheadb, bheadg, out);
}

// Round 5
// 269.580 us; speedup vs baseline: 1.1728x; 1.1728x over previous
//
#include <hip/hip_runtime.h>
#include <hip/hip_bf16.h>
#include <math.h>

// B=128, K=64, M=2048, QD=128, AD=128, H=256, C=32
// out: y [0,786432) | type_logits [786432,9175040) | weight_logits [9175040,9437184)

typedef __attribute__((ext_vector_type(8))) short short8;
typedef __attribute__((ext_vector_type(4))) float f32x4;

__device__ __forceinline__ unsigned short bf16_rne(float f){
    union { float f; unsigned u; } v; v.f = f;
    return (unsigned short)((v.u + 0x7FFFu + ((v.u >> 16) & 1u)) >> 16);
}
// packed 2xfp32 -> 2xbf16 (RNE), low word = a
__device__ __forceinline__ unsigned pk_bf16(float a, float b){
    float2 t; t.x = a; t.y = b;
    __hip_bfloat162 h = __float22bfloat162_rn(t);
    union { __hip_bfloat162 h; unsigned u; } cv; cv.h = h;
    return cv.u;
}

// exact-erf gelu (A&S 7.1.26) - prep paths
__device__ __forceinline__ float gelu_f(float x){
    float z  = x * 0.70710678118654752f;
    float az = fabsf(z);
    float t  = __builtin_amdgcn_rcpf(1.0f + 0.3275911f * az);
    float p  = t*(0.254829592f + t*(-0.284496736f + t*(1.421413741f + t*(-1.453152027f + t*1.061405429f))));
    float e  = __expf(-az*az);
    float er = copysignf(1.0f - p*e, z);
    return 0.5f * x * (1.0f + er);
}

// tanh-form gelu; error <1e-5 for |x|<0.5 (our preacts are O(0.1))
__device__ __forceinline__ float gelu_fast(float x){
    float x2 = x*x;
    float p  = fmaf(x2, -0.1029433f, -2.3022082f);
    float u  = x*p;
    float e  = __builtin_amdgcn_exp2f(u);
    float r  = __builtin_amdgcn_rcpf(1.0f + e);
    return x*r;
}

// ---------------- fused prep kernel 1 (436 blocks) ----------------
// [0,32) inv | 32 v,s0 | [33,97) w2->bf16 | [97,131) head fold | [131,163) w1q->bf16
// [163,227) query->bf16 | [227,291) gmW2^T | [291,355) gmW3^T | [355,419) w1g^T
// [419,435) gmW1^T | 435 w385
__global__ void k_pre1(const float* __restrict__ g, const float* __restrict__ qW,
                       const float* __restrict__ qb, const float* __restrict__ kW,
                       const float* __restrict__ query, const float* __restrict__ pmW1,
                       const float* __restrict__ pmW2, const float* __restrict__ pmW3,
                       const float* __restrict__ pmb3,
                       const float* __restrict__ gmW1, const float* __restrict__ gmW2,
                       const float* __restrict__ gmW3,
                       const float* __restrict__ tW, const float* __restrict__ tb,
                       const float* __restrict__ wW, const float* __restrict__ wb,
                       const float* __restrict__ cW, const float* __restrict__ cb,
                       float* __restrict__ invg, float* __restrict__ vg, float* __restrict__ s0g,
                       unsigned short* __restrict__ w2b, unsigned short* __restrict__ wheadb,
                       float* __restrict__ bheadg,
                       unsigned short* __restrict__ w1qb, unsigned short* __restrict__ queryb,
                       float* __restrict__ gmW1t, float* __restrict__ gmW2t,
                       float* __restrict__ gmW3t, float* __restrict__ w1gt,
                       float* __restrict__ w385g) {
    const int bid = blockIdx.x, tid = threadIdx.x;
    if (bid < 32) {
        int idx = bid*256 + tid;
        const float* p = g + idx*3;
        invg[idx] = sqrtf(p[0]*p[0] + p[1]*p[1] + p[2]*p[2]);
    } else if (bid == 32) {
        if (tid < 128) {
            float acc = 0.f;
            for (int d = 0; d < 128; ++d) acc += qW[d*128 + tid] * kW[d];
            vg[tid] = acc;
            if (tid == 0) {
                float s = 0.f;
                for (int d = 0; d < 128; ++d) s += qb[d] * kW[d];
                *s0g = s;
            }
        }
    } else if (bid < 97) {
        int o = (bid - 33)*1024 + tid*4;
        float4 x = *(const float4*)&pmW2[o];
        union { unsigned short u[4]; uint2 v; } r;
        r.u[0] = bf16_rne(x.x); r.u[1] = bf16_rne(x.y);
        r.u[2] = bf16_rne(x.z); r.u[3] = bf16_rne(x.w);
        *(uint2*)&w2b[o] = r.v;
    } else if (bid < 131) {
        __shared__ float hw[256];
        int c = bid - 97;
        const float* src = (c < 32) ? (tW + c*256) : ((c == 32) ? wW : cW);
        hw[tid] = src[tid];
        __syncthreads();
        float acc = 0.f;
        for (int j = 0; j < 256; ++j) acc += hw[j] * pmW3[j*256 + tid];
        wheadb[c*256 + tid] = bf16_rne(acc);
        if (tid == 0) {
            float bacc = (c < 32) ? tb[c] : ((c == 32) ? wb[0] : cb[0]);
            for (int j = 0; j < 256; ++j) bacc += hw[j] * pmb3[j];
            bheadg[c] = bacc;
        }
    } else if (bid < 163) {
        int o = (bid - 131)*1024 + tid*4;  // w1qb[n*128+k] = pmW1[n*385+256+k]
        int n = o >> 7, k = o & 127;
        union { unsigned short u[4]; uint2 v; } r;
        #pragma unroll
        for (int i = 0; i < 4; ++i) r.u[i] = bf16_rne(pmW1[n*385 + 256 + k + i]);
        *(uint2*)&w1qb[o] = r.v;
    } else if (bid < 227) {
        int base = (bid - 163)*4096 + tid*4;
        #pragma unroll
        for (int it = 0; it < 4; ++it) {
            int o = base + it*1024;
            float4 x = *(const float4*)&query[o];
            union { unsigned short u[4]; uint2 v; } r;
            r.u[0] = bf16_rne(x.x); r.u[1] = bf16_rne(x.y);
            r.u[2] = bf16_rne(x.z); r.u[3] = bf16_rne(x.w);
            *(uint2*)&queryb[o] = r.v;
        }
    } else if (bid < 291) {
        int o = (bid - 227)*1024 + tid*4;  // gmW2t[i*256+j] = gmW2[j*256+i]
        int i = o >> 8, j = o & 255;
        float4 r = { gmW2[j*256+i], gmW2[(j+1)*256+i], gmW2[(j+2)*256+i], gmW2[(j+3)*256+i] };
        *(float4*)&gmW2t[o] = r;
    } else if (bid < 355) {
        int o = (bid - 291)*1024 + tid*4;
        int i = o >> 8, j = o & 255;
        float4 r = { gmW3[j*256+i], gmW3[(j+1)*256+i], gmW3[(j+2)*256+i], gmW3[(j+3)*256+i] };
        *(float4*)&gmW3t[o] = r;
    } else if (bid < 419) {
        int o = (bid - 355)*1024 + tid*4;  // w1gt[i*256+j] = pmW1[j*385+i]
        int i = o >> 8, j = o & 255;
        float4 r = { pmW1[j*385+i], pmW1[(j+1)*385+i], pmW1[(j+2)*385+i], pmW1[(j+3)*385+i] };
        *(float4*)&w1gt[o] = r;
    } else if (bid < 435) {
        int o = (bid - 419)*1024 + tid*4;  // gmW1t[k*256+j] = gmW1[j*64+k]
        int k = o >> 8, j = o & 255;
        float4 r = { gmW1[j*64+k], gmW1[(j+1)*64+k], gmW1[(j+2)*64+k], gmW1[(j+3)*64+k] };
        *(float4*)&gmW1t[o] = r;
    } else {
        w385g[tid] = pmW1[tid*385 + 384];
    }
}

// ---------------- fused prep kernel 2 (168 blocks) ----------------
// [0,8) a[m] | [8,136) global-MLP + u1 fold | [136,168) u2 = query @ W1q^T (MFMA)
__global__ void k_pre2(const float* __restrict__ query, const float* __restrict__ vg,
                       const float* __restrict__ s0g, const float* __restrict__ invg,
                       const float* __restrict__ gmW1t, const float* __restrict__ gmb1,
                       const float* __restrict__ gmW2t, const float* __restrict__ gmb2,
                       const float* __restrict__ gmW3t, const float* __restrict__ gmb3,
                       const float* __restrict__ w1gt, const float* __restrict__ pmb1,
                       const unsigned short* __restrict__ queryb,
                       const unsigned short* __restrict__ w1qb,
                       float* __restrict__ ag, float* __restrict__ u1g,
                       float* __restrict__ u2g) {
    const int bid = blockIdx.x, tid = threadIdx.x;
    if (bid < 8) {
        __shared__ float vs[128];
        if (tid < 128) vs[tid] = vg[tid];
        __syncthreads();
        int m = bid*256 + tid;
        const float4* qp = (const float4*)(query + m*128);
        float acc = *s0g;
        #pragma unroll 8
        for (int e4 = 0; e4 < 32; ++e4) {
            float4 q = qp[e4];
            acc += q.x*vs[e4*4] + q.y*vs[e4*4+1] + q.z*vs[e4*4+2] + q.w*vs[e4*4+3];
        }
        ag[m] = acc * 0.08838834764831845f; // 1/sqrt(128)
    } else if (bid < 136) {
        __shared__ float s_in[64];
        __shared__ float s_h[256];
        __shared__ float s_h2[256];
        int b = bid - 8;
        if (tid < 64) s_in[tid] = invg[b*64 + tid];
        __syncthreads();
        float acc = gmb1[tid];
        #pragma unroll 8
        for (int k = 0; k < 64; ++k) acc += gmW1t[k*256 + tid] * s_in[k];
        s_h[tid] = gelu_f(acc);
        __syncthreads();
        acc = gmb2[tid];
        #pragma unroll 8
        for (int i = 0; i < 256; ++i) acc += gmW2t[i*256 + tid] * s_h[i];
        s_h2[tid] = gelu_f(acc);
        __syncthreads();
        acc = gmb3[tid];
        #pragma unroll 8
        for (int i = 0; i < 256; ++i) acc += gmW3t[i*256 + tid] * s_h2[i];
        __syncthreads();
        s_h[tid] = acc;        // global_s
        __syncthreads();
        float u = pmb1[tid];
        #pragma unroll 8
        for (int i = 0; i < 256; ++i) u += w1gt[i*256 + tid] * s_h[i];
        u1g[b*256 + tid] = u;
    } else {
        // u2 tile: 64 rows of m, full 256 cols, K=128. MFMA.
        const int m0 = (bid - 136)*64;
        const int w = tid >> 6, lane = tid & 63;
        const int q = lane >> 4, ln = lane & 15;
        f32x4 acc[4][4];
        #pragma unroll
        for (int mt = 0; mt < 4; ++mt)
            #pragma unroll
            for (int nt = 0; nt < 4; ++nt) acc[mt][nt] = (f32x4){0.f,0.f,0.f,0.f};
        #pragma unroll
        for (int kk = 0; kk < 4; ++kk) {
            const int kc = kk*32 + q*8;
            short8 afr[4], bfr[4];
            #pragma unroll
            for (int mt = 0; mt < 4; ++mt)
                afr[mt] = *(const short8*)&queryb[(m0 + mt*16 + ln)*128 + kc];
            #pragma unroll
            for (int nt = 0; nt < 4; ++nt)
                bfr[nt] = *(const short8*)&w1qb[(w*64 + nt*16 + ln)*128 + kc];
            #pragma unroll
            for (int mt = 0; mt < 4; ++mt)
                #pragma unroll
                for (int nt = 0; nt < 4; ++nt)
                    acc[mt][nt] = __builtin_amdgcn_mfma_f32_16x16x32_bf16(afr[mt], bfr[nt], acc[mt][nt], 0, 0, 0);
        }
        #pragma unroll
        for (int mt = 0; mt < 4; ++mt)
            #pragma unroll
            for (int nt = 0; nt < 4; ++nt) {
                const int n = w*64 + nt*16 + ln;
                #pragma unroll
                for (int rg = 0; rg < 4; ++rg)
                    u2g[(size_t)(m0 + mt*16 + q*4 + rg)*256 + n] = acc[mt][nt][rg];
            }
    }
}

// ---------------- main fused kernel ----------------
// One block = 64 rows (same b). 4096 blocks x 256 threads.
__global__ __launch_bounds__(256, 4)
void k_main(const float* __restrict__ g,
            const float* __restrict__ invg, const float* __restrict__ ag,
            const float* __restrict__ u1g, const float* __restrict__ u2g,
            const float* __restrict__ w385g, const float* __restrict__ pmb2,
            const unsigned short* __restrict__ w2b, const unsigned short* __restrict__ wheadb,
            const float* __restrict__ bheadg, float* __restrict__ out) {
    // row stride 264 shorts (132 dwords == 4 mod 32 -> 2-way read aliasing, free)
    __shared__ __align__(16) unsigned short hb[64*264];  // h1, later h2
    __shared__ __align__(16) float u1s[256], w385s[256], pmb2s[256];
    __shared__ float invs[64], gsl[192], ainv_s[64], y0s[192];

    const int tid = threadIdx.x;
    const int bid = blockIdx.x;
    const int b  = bid >> 5;           // 32 tiles per b
    const int m0 = (bid & 31) << 6;    // 64 rows

    if (tid < 64)  invs[tid] = invg[b*64 + tid];
    if (tid < 192) gsl[tid]  = g[b*192 + tid];
    u1s[tid]   = u1g[b*256 + tid];
    w385s[tid] = w385g[tid];
    pmb2s[tid] = pmb2[tid];
    __syncthreads();

    // ---- phase 1: rank-1 softmax over k; 4 threads per row ----
    {
        const int r = tid >> 2, sub = tid & 3;
        const float am = ag[m0 + r];
        const int kb = sub * 16;
        float mx = -1e30f;
        #pragma unroll
        for (int i = 0; i < 16; ++i) mx = fmaxf(mx, invs[kb + i] * am);
        #pragma unroll
        for (int d = 1; d < 4; d <<= 1) mx = fmaxf(mx, __shfl_xor(mx, d, 64));
        float den = 0.f, ai = 0.f, y0 = 0.f, y1 = 0.f, y2 = 0.f;
        #pragma unroll
        for (int i = 0; i < 16; ++i) {
            const int k = kb + i;
            const float iv = invs[k];
            const float e = __expf(iv * am - mx);
            den += e; ai += e * iv;
            y0 += e * gsl[k*3+0]; y1 += e * gsl[k*3+1]; y2 += e * gsl[k*3+2];
        }
        #pragma unroll
        for (int d = 1; d < 4; d <<= 1) {
            den += __shfl_xor(den, d, 64);
            ai  += __shfl_xor(ai , d, 64);
            y0  += __shfl_xor(y0 , d, 64);
            y1  += __shfl_xor(y1 , d, 64);
            y2  += __shfl_xor(y2 , d, 64);
        }
        if (sub == 0) {
            const float id = 1.0f / den;
            ainv_s[r] = ai * id;
            y0s[r*3+0] = y0*id; y0s[r*3+1] = y1*id; y0s[r*3+2] = y2*id;
        }
    }
    __syncthreads();

    // ---- phase 1b: h1 = gelu(u2[m] + u1[b] + ainv*w385) -> bf16 LDS ----
    // Coalesced: 16 lanes x float4 = contiguous 256B per row-quad.
    {
        const int ln16 = tid & 15, rbase = tid >> 4;  // rbase 0..15
        #pragma unroll
        for (int rr = 0; rr < 4; ++rr) {
            const int r = rr*16 + rbase;
            const float aiv = ainv_s[r];
            const float* u2p = u2g + (size_t)(m0 + r)*256;
            #pragma unroll
            for (int k = 0; k < 4; ++k) {
                const int c = ln16*4 + k*64;
                float4 x  = *(const float4*)&u2p[c];
                float4 uv = *(const float4*)&u1s[c];
                float4 wv = *(const float4*)&w385s[c];
                float g0 = gelu_fast(x.x + uv.x + aiv*wv.x);
                float g1 = gelu_fast(x.y + uv.y + aiv*wv.y);
                float g2 = gelu_fast(x.z + uv.z + aiv*wv.z);
                float g3 = gelu_fast(x.w + uv.w + aiv*wv.w);
                uint2 pk; pk.x = pk_bf16(g0, g1); pk.y = pk_bf16(g2, g3);
                *(uint2*)&hb[r*264 + c] = pk;
            }
        }
    }
    __syncthreads();

    const int w = tid >> 6, lane = tid & 63;
    const int q = lane >> 4, ln = lane & 15;

    // ---- phase 2: h2 = gelu(H1 @ W2^T + b2), 64x256x256 bf16 MFMA, 1-deep B prefetch ----
    f32x4 acc[4][4];
    #pragma unroll
    for (int mt = 0; mt < 4; ++mt)
        #pragma unroll
        for (int nt = 0; nt < 4; ++nt) acc[mt][nt] = (f32x4){0.f,0.f,0.f,0.f};

    {
        const unsigned short* w2p = w2b + (w*64 + ln)*256 + q*8;
        short8 bcur[4], bnxt[4];
        #pragma unroll
        for (int nt = 0; nt < 4; ++nt) bcur[nt] = *(const short8*)(w2p + nt*4096);
        #pragma unroll
        for (int kk = 0; kk < 8; ++kk) {
            if (kk < 7) {
                #pragma unroll
                for (int nt = 0; nt < 4; ++nt)
                    bnxt[nt] = *(const short8*)(w2p + nt*4096 + (kk+1)*32);
            }
            short8 afrag[4];
            const int kc = kk*32 + q*8;
            #pragma unroll
            for (int mt = 0; mt < 4; ++mt)
                afrag[mt] = *(const short8*)&hb[(mt*16 + ln)*264 + kc];
            #pragma unroll
            for (int mt = 0; mt < 4; ++mt)
                #pragma unroll
                for (int nt = 0; nt < 4; ++nt)
                    acc[mt][nt] = __builtin_amdgcn_mfma_f32_16x16x32_bf16(afrag[mt], bcur[nt], acc[mt][nt], 0, 0, 0);
            #pragma unroll
            for (int nt = 0; nt < 4; ++nt) bcur[nt] = bnxt[nt];
        }
    }
    __syncthreads();  // all h1 reads done

    // h2 = gelu(acc + b2) -> bf16 back into hb (packed cvt, b16 writes)
    #pragma unroll
    for (int mt = 0; mt < 4; ++mt) {
        #pragma unroll
        for (int nt = 0; nt < 4; ++nt) {
            const int n = w*64 + nt*16 + ln;
            const float bb = pmb2s[n];
            const int r0 = mt*16 + q*4;
            float h0 = gelu_fast(acc[mt][nt][0] + bb);
            float h1 = gelu_fast(acc[mt][nt][1] + bb);
            float h2 = gelu_fast(acc[mt][nt][2] + bb);
            float h3 = gelu_fast(acc[mt][nt][3] + bb);
            unsigned p01 = pk_bf16(h0, h1);
            unsigned p23 = pk_bf16(h2, h3);
            hb[(r0+0)*264 + n] = (unsigned short)(p01 & 0xFFFF);
            hb[(r0+1)*264 + n] = (unsigned short)(p01 >> 16);
            hb[(r0+2)*264 + n] = (unsigned short)(p23 & 0xFFFF);
            hb[(r0+3)*264 + n] = (unsigned short)(p23 >> 16);
        }
    }

    // preload phase-3 A frags (whead) BEFORE the barrier: vmcnt drain makes this a prefetch
    const int cb2 = (ln < 2) ? (32 + ln) : 33;
    const unsigned short* whp = wheadb + q*8;
    short8 wf0 = *(const short8*)(whp +  ln      *256);
    short8 wf1 = *(const short8*)(whp + (16 + ln)*256);
    short8 wf2 = *(const short8*)(whp +  cb2     *256);
    __syncthreads();

    // ---- phase 3: heads: D[c][r] = Whead[c,:] . h2[r,:]; wave w owns rows w*16..+15 ----
    f32x4 accA0 = {0.f,0.f,0.f,0.f}, accA1 = {0.f,0.f,0.f,0.f}, accB = {0.f,0.f,0.f,0.f};
    const int rr = w*16 + ln;
    #pragma unroll
    for (int kk = 0; kk < 8; ++kk) {
        short8 wn0, wn1, wn2;
        if (kk < 7) {
            wn0 = *(const short8*)(whp +  ln      *256 + (kk+1)*32);
            wn1 = *(const short8*)(whp + (16 + ln)*256 + (kk+1)*32);
            wn2 = *(const short8*)(whp +  cb2     *256 + (kk+1)*32);
        }
        short8 bh = *(const short8*)&hb[rr*264 + kk*32 + q*8];
        accA0 = __builtin_amdgcn_mfma_f32_16x16x32_bf16(wf0, bh, accA0, 0, 0, 0);
        accA1 = __builtin_amdgcn_mfma_f32_16x16x32_bf16(wf1, bh, accA1, 0, 0, 0);
        accB  = __builtin_amdgcn_mfma_f32_16x16x32_bf16(wf2, bh, accB , 0, 0, 0);
        wf0 = wn0; wf1 = wn1; wf2 = wn2;
    }
    {
        const size_t row = (size_t)b*2048 + m0 + rr;
        const int c0 = q*4;
        f32x4 r0 = accA0 + *(const f32x4*)&bheadg[c0];
        f32x4 r1 = accA1 + *(const f32x4*)&bheadg[16 + c0];
        *(f32x4*)&out[786432 + row*32 + c0]      = r0;
        *(f32x4*)&out[786432 + row*32 + 16 + c0] = r1;
        if (q == 0) {
            out[9175040 + row] = accB[0] + bheadg[32];
            float gv = accB[1] + bheadg[33];
            float gt = 1.0f / (1.0f + __expf(-gv));
            gt = fminf(fmaxf(gt, 0.0f), 1.0f);
            float* yo = out + row*3;
            yo[0] = y0s[rr*3+0] * gt;
            yo[1] = y0s[rr*3+1] * gt;
            yo[2] = y0s[rr*3+2] * gt;
        }
    }
}

// ---------------- launcher ----------------
extern "C" void kernel_launch(void* const* d_in, const int* in_sizes, int n_in,
                              void* d_out, int out_size, void* d_ws, size_t ws_size,
                              hipStream_t stream) {
    const float* g     = (const float*)d_in[0];
    const float* query = (const float*)d_in[1];
    const float* qW    = (const float*)d_in[2];
    const float* qb    = (const float*)d_in[3];
    const float* kW    = (const float*)d_in[4];
    // d_in[5] = kb (cancels in softmax)
    const float* gmW1  = (const float*)d_in[6];
    const float* gmb1  = (const float*)d_in[7];
    const float* gmW2  = (const float*)d_in[8];
    const float* gmb2  = (const float*)d_in[9];
    const float* gmW3  = (const float*)d_in[10];
    const float* gmb3  = (const float*)d_in[11];
    const float* pmW1  = (const float*)d_in[12];
    const float* pmb1  = (const float*)d_in[13];
    const float* pmW2  = (const float*)d_in[14];
    const float* pmb2  = (const float*)d_in[15];
    const float* pmW3  = (const float*)d_in[16];
    const float* pmb3  = (const float*)d_in[17];
    const float* tW    = (const float*)d_in[18];
    const float* tb    = (const float*)d_in[19];
    const float* wW    = (const float*)d_in[20];
    const float* wb    = (const float*)d_in[21];
    const float* cW    = (const float*)d_in[22];
    const float* cb    = (const float*)d_in[23];
    float* out = (float*)d_out;

    // workspace layout (float slots)
    float* ws    = (float*)d_ws;
    float* invg  = ws;                                       // 8192
    float* ag    = ws + 8192;                                // 2048
    float* vg    = ws + 10240;                               // 128
    float* s0g   = ws + 10368;                               // pad -> 10496
    float* u1g   = ws + 10496;                               // 32768 -> 43264
    float* gmW1t = ws + 43264;                               // 16384 -> 59648
    float* gmW2t = ws + 59648;                               // 65536 -> 125184
    float* gmW3t = ws + 125184;                              // 65536 -> 190720
    float* w1gt  = ws + 190720;                              // 65536 -> 256256
    float* w385g = ws + 256256;                              // 256 -> 256512
    float* bheadg= ws + 256512;                              // 64 -> 256576
    unsigned short* w2b    = (unsigned short*)(ws + 256576); // 65536 sh -> 289344
    unsigned short* wheadb = (unsigned short*)(ws + 289344); // 8704 sh -> 293696
    unsigned short* w1qb   = (unsigned short*)(ws + 293696); // 32768 sh -> 310080
    unsigned short* queryb = (unsigned short*)(ws + 310080); // 262144 sh -> 441152
    float* u2g   = ws + 441152;                              // 524288 -> 965440 (~3.9 MB)

    hipLaunchKernelGGL(k_pre1, dim3(436), dim3(256), 0, stream,
                       g, qW, qb, kW, query, pmW1, pmW2, pmW3, pmb3,
                       gmW1, gmW2, gmW3,
                       tW, tb, wW, wb, cW, cb,
                       invg, vg, s0g, w2b, wheadb, bheadg,
                       w1qb, queryb, gmW1t, gmW2t, gmW3t, w1gt, w385g);
    hipLaunchKernelGGL(k_pre2, dim3(168), dim3(256), 0, stream,
                       query, vg, s0g, invg,
                       gmW1t, gmb1, gmW2t, gmb2, gmW3t, gmb3, w1gt, pmb1,
                       queryb, w1qb,
                       ag, u1g, u2g);
    hipLaunchKernelGGL(k_main, dim3(4096), dim3(256), 0, stream,
                       g, invg, ag, u1g, u2g, w385g, pmb2,
                       w2b, wheadb, bheadg, out);
}

// Round 6
// 255.371 us; speedup vs baseline: 1.2381x; 1.0556x over previous
//
#include <hip/hip_runtime.h>
#include <hip/hip_bf16.h>
#include <math.h>

// B=128, K=64, M=2048, QD=128, AD=128, H=256, C=32
// out: y [0,786432) | type_logits [786432,9175040) | weight_logits [9175040,9437184)

typedef __attribute__((ext_vector_type(8))) short short8;
typedef __attribute__((ext_vector_type(4))) float f32x4;

__device__ __forceinline__ unsigned short bf16_rne(float f){
    union { float f; unsigned u; } v; v.f = f;
    return (unsigned short)((v.u + 0x7FFFu + ((v.u >> 16) & 1u)) >> 16);
}
__device__ __forceinline__ unsigned pk_bf16(float a, float b){
    float2 t; t.x = a; t.y = b;
    __hip_bfloat162 h = __float22bfloat162_rn(t);
    union { __hip_bfloat162 h; unsigned u; } cv; cv.h = h;
    return cv.u;
}
// 8 consecutive fp32 (16B-aligned) -> short8 bf16
__device__ __forceinline__ short8 cvt8_f4(const float* __restrict__ p){
    float4 a = *(const float4*)p;
    float4 b = *(const float4*)(p + 4);
    short8 s;
    s[0]=(short)bf16_rne(a.x); s[1]=(short)bf16_rne(a.y);
    s[2]=(short)bf16_rne(a.z); s[3]=(short)bf16_rne(a.w);
    s[4]=(short)bf16_rne(b.x); s[5]=(short)bf16_rne(b.y);
    s[6]=(short)bf16_rne(b.z); s[7]=(short)bf16_rne(b.w);
    return s;
}
// 8 consecutive fp32 (unaligned ok, scalar loads) -> short8 bf16
__device__ __forceinline__ short8 cvt8_s(const float* __restrict__ p){
    short8 s;
    #pragma unroll
    for (int i = 0; i < 8; ++i) s[i] = (short)bf16_rne(p[i]);
    return s;
}

// exact-erf gelu (A&S 7.1.26)
__device__ __forceinline__ float gelu_f(float x){
    float z  = x * 0.70710678118654752f;
    float az = fabsf(z);
    float t  = __builtin_amdgcn_rcpf(1.0f + 0.3275911f * az);
    float p  = t*(0.254829592f + t*(-0.284496736f + t*(1.421413741f + t*(-1.453152027f + t*1.061405429f))));
    float e  = __expf(-az*az);
    float er = copysignf(1.0f - p*e, z);
    return 0.5f * x * (1.0f + er);
}
// tanh-form gelu; error <1e-5 for |x|<0.5 (point-mlp preacts are O(0.1))
__device__ __forceinline__ float gelu_fast(float x){
    float x2 = x*x;
    float p  = fmaf(x2, -0.1029433f, -2.3022082f);
    float u  = x*p;
    float e  = __builtin_amdgcn_exp2f(u);
    float r  = __builtin_amdgcn_rcpf(1.0f + e);
    return x*r;
}

// =================== single fused prep kernel (173 independent blocks) ===================
// [0,32) inv | [32,96) w2->bf16 | [96,130) head fold | 130 w385 | [131,139) v,s0,a[m]
// [139,141) global-MLP+u1 via MFMA (inline cvt) | [141,173) u2 = query @ W1q^T via MFMA
__global__ __launch_bounds__(256)
void k_prep(const float* __restrict__ g, const float* __restrict__ qW,
            const float* __restrict__ qb, const float* __restrict__ kW,
            const float* __restrict__ query, const float* __restrict__ pmW1,
            const float* __restrict__ pmb1,
            const float* __restrict__ pmW2, const float* __restrict__ pmW3,
            const float* __restrict__ pmb3,
            const float* __restrict__ gmW1, const float* __restrict__ gmb1,
            const float* __restrict__ gmW2, const float* __restrict__ gmb2,
            const float* __restrict__ gmW3, const float* __restrict__ gmb3,
            const float* __restrict__ tW, const float* __restrict__ tb,
            const float* __restrict__ wW, const float* __restrict__ wb,
            const float* __restrict__ cW, const float* __restrict__ cb,
            float* __restrict__ invg, float* __restrict__ ag,
            float* __restrict__ u1g, float* __restrict__ u2g,
            unsigned short* __restrict__ w2b, unsigned short* __restrict__ wheadb,
            float* __restrict__ bheadg, float* __restrict__ w385g) {
    __shared__ __align__(16) unsigned char smem[87040];
    const int bid = blockIdx.x, tid = threadIdx.x;
    const int w = tid >> 6, lane = tid & 63, q = lane >> 4, ln = lane & 15;

    if (bid < 32) {
        // ---- inv[b,k] = ||g[b,k,:]|| ----
        int idx = bid*256 + tid;
        const float* p = g + idx*3;
        invg[idx] = sqrtf(p[0]*p[0] + p[1]*p[1] + p[2]*p[2]);
    } else if (bid < 96) {
        // ---- w2 -> bf16 ([n][k] row-major = B-operand layout) ----
        int o = (bid - 32)*1024 + tid*4;
        float4 x = *(const float4*)&pmW2[o];
        union { unsigned short u[4]; uint2 v; } r;
        r.u[0] = bf16_rne(x.x); r.u[1] = bf16_rne(x.y);
        r.u[2] = bf16_rne(x.z); r.u[3] = bf16_rne(x.w);
        *(uint2*)&w2b[o] = r.v;
    } else if (bid < 130) {
        // ---- Whead[c,:] = Hw[c,:] @ pm_W3; bhead[c] folded bias ----
        float* hw = (float*)smem;
        int c = bid - 96;
        const float* src = (c < 32) ? (tW + c*256) : ((c == 32) ? wW : cW);
        hw[tid] = src[tid];
        __syncthreads();
        float acc = 0.f;
        for (int j = 0; j < 256; ++j) acc += hw[j] * pmW3[j*256 + tid];
        wheadb[c*256 + tid] = bf16_rne(acc);
        if (tid == 0) {
            float bacc = (c < 32) ? tb[c] : ((c == 32) ? wb[0] : cb[0]);
            for (int j = 0; j < 256; ++j) bacc += hw[j] * pmb3[j];
            bheadg[c] = bacc;
        }
    } else if (bid == 130) {
        w385g[tid] = pmW1[tid*385 + 384];
    } else if (bid < 139) {
        // ---- a[m] = (query[m].v + s0)/sqrt(128), v/s0 computed inline ----
        float* kws = (float*)smem;        // 128
        float* vs  = kws + 128;           // 128
        float* red = vs  + 128;           // 128
        if (tid < 128) kws[tid] = kW[tid];
        __syncthreads();
        if (tid < 128) {
            float acc = 0.f;
            for (int d = 0; d < 128; ++d) acc += qW[d*128 + tid] * kws[d];
            vs[tid] = acc;
            red[tid] = qb[tid] * kws[tid];
        }
        __syncthreads();
        float s0 = 0.f;
        #pragma unroll 8
        for (int i = 0; i < 128; ++i) s0 += red[i];
        int m = (bid - 131)*256 + tid;
        const float4* qp = (const float4*)(query + m*128);
        float acc = s0;
        #pragma unroll 8
        for (int e4 = 0; e4 < 32; ++e4) {
            float4 qv = qp[e4];
            acc += qv.x*vs[e4*4] + qv.y*vs[e4*4+1] + qv.z*vs[e4*4+2] + qv.w*vs[e4*4+3];
        }
        ag[m] = acc * 0.08838834764831845f;
    } else if (bid < 141) {
        // ---- global MLP (64->256->256->256) + u1 fold, 64 b-rows per block, MFMA ----
        unsigned short* invA = (unsigned short*)smem;            // 64 x 72
        unsigned short* hA   = (unsigned short*)(smem + 9216);   // 64 x 264
        unsigned short* hB   = (unsigned short*)(smem + 43008);  // 64 x 264
        const int b0 = (bid - 139)*64;
        // stage inv (bf16) computed from g
        for (int i = tid; i < 4096; i += 256) {
            int r = i >> 6, k = i & 63;
            const float* p = g + ((size_t)(b0 + r)*64 + k)*3;
            invA[r*72 + k] = bf16_rne(sqrtf(p[0]*p[0] + p[1]*p[1] + p[2]*p[2]));
        }
        __syncthreads();

        f32x4 acc[4][4];
        // ---- layer 1: K=64, B=gmW1 rows (aligned) ----
        #pragma unroll
        for (int mt = 0; mt < 4; ++mt)
            #pragma unroll
            for (int nt = 0; nt < 4; ++nt) acc[mt][nt] = (f32x4){0.f,0.f,0.f,0.f};
        #pragma unroll
        for (int kk = 0; kk < 2; ++kk) {
            const int kc = kk*32 + q*8;
            short8 af[4], bf_[4];
            #pragma unroll
            for (int mt = 0; mt < 4; ++mt) af[mt] = *(const short8*)&invA[(mt*16 + ln)*72 + kc];
            #pragma unroll
            for (int nt = 0; nt < 4; ++nt) bf_[nt] = cvt8_f4(gmW1 + (w*64 + nt*16 + ln)*64 + kc);
            #pragma unroll
            for (int mt = 0; mt < 4; ++mt)
                #pragma unroll
                for (int nt = 0; nt < 4; ++nt)
                    acc[mt][nt] = __builtin_amdgcn_mfma_f32_16x16x32_bf16(af[mt], bf_[nt], acc[mt][nt], 0, 0, 0);
        }
        #pragma unroll
        for (int mt = 0; mt < 4; ++mt)
            #pragma unroll
            for (int nt = 0; nt < 4; ++nt) {
                const int n = w*64 + nt*16 + ln;
                const float bb = gmb1[n];
                #pragma unroll
                for (int rg = 0; rg < 4; ++rg)
                    hA[(mt*16 + q*4 + rg)*264 + n] = bf16_rne(gelu_f(acc[mt][nt][rg] + bb));
            }
        __syncthreads();
        // ---- layer 2: K=256, B=gmW2 rows ----
        #pragma unroll
        for (int mt = 0; mt < 4; ++mt)
            #pragma unroll
            for (int nt = 0; nt < 4; ++nt) acc[mt][nt] = (f32x4){0.f,0.f,0.f,0.f};
        for (int kk = 0; kk < 8; ++kk) {
            const int kc = kk*32 + q*8;
            short8 af[4], bf_[4];
            #pragma unroll
            for (int mt = 0; mt < 4; ++mt) af[mt] = *(const short8*)&hA[(mt*16 + ln)*264 + kc];
            #pragma unroll
            for (int nt = 0; nt < 4; ++nt) bf_[nt] = cvt8_f4(gmW2 + (w*64 + nt*16 + ln)*256 + kc);
            #pragma unroll
            for (int mt = 0; mt < 4; ++mt)
                #pragma unroll
                for (int nt = 0; nt < 4; ++nt)
                    acc[mt][nt] = __builtin_amdgcn_mfma_f32_16x16x32_bf16(af[mt], bf_[nt], acc[mt][nt], 0, 0, 0);
        }
        __syncthreads();
        #pragma unroll
        for (int mt = 0; mt < 4; ++mt)
            #pragma unroll
            for (int nt = 0; nt < 4; ++nt) {
                const int n = w*64 + nt*16 + ln;
                const float bb = gmb2[n];
                #pragma unroll
                for (int rg = 0; rg < 4; ++rg)
                    hB[(mt*16 + q*4 + rg)*264 + n] = bf16_rne(gelu_f(acc[mt][nt][rg] + bb));
            }
        __syncthreads();
        // ---- layer 3: K=256, B=gmW3 rows -> global_s into hA ----
        #pragma unroll
        for (int mt = 0; mt < 4; ++mt)
            #pragma unroll
            for (int nt = 0; nt < 4; ++nt) acc[mt][nt] = (f32x4){0.f,0.f,0.f,0.f};
        for (int kk = 0; kk < 8; ++kk) {
            const int kc = kk*32 + q*8;
            short8 af[4], bf_[4];
            #pragma unroll
            for (int mt = 0; mt < 4; ++mt) af[mt] = *(const short8*)&hB[(mt*16 + ln)*264 + kc];
            #pragma unroll
            for (int nt = 0; nt < 4; ++nt) bf_[nt] = cvt8_f4(gmW3 + (w*64 + nt*16 + ln)*256 + kc);
            #pragma unroll
            for (int mt = 0; mt < 4; ++mt)
                #pragma unroll
                for (int nt = 0; nt < 4; ++nt)
                    acc[mt][nt] = __builtin_amdgcn_mfma_f32_16x16x32_bf16(af[mt], bf_[nt], acc[mt][nt], 0, 0, 0);
        }
        __syncthreads();
        #pragma unroll
        for (int mt = 0; mt < 4; ++mt)
            #pragma unroll
            for (int nt = 0; nt < 4; ++nt) {
                const int n = w*64 + nt*16 + ln;
                const float bb = gmb3[n];
                #pragma unroll
                for (int rg = 0; rg < 4; ++rg)
                    hA[(mt*16 + q*4 + rg)*264 + n] = bf16_rne(acc[mt][nt][rg] + bb);  // no gelu
            }
        __syncthreads();
        // ---- u1 fold: u1 = global_s @ pmW1[:, :256]^T + pmb1 (B rows stride 385, unaligned) ----
        #pragma unroll
        for (int mt = 0; mt < 4; ++mt)
            #pragma unroll
            for (int nt = 0; nt < 4; ++nt) acc[mt][nt] = (f32x4){0.f,0.f,0.f,0.f};
        for (int kk = 0; kk < 8; ++kk) {
            const int kc = kk*32 + q*8;
            short8 af[4], bf_[4];
            #pragma unroll
            for (int mt = 0; mt < 4; ++mt) af[mt] = *(const short8*)&hA[(mt*16 + ln)*264 + kc];
            #pragma unroll
            for (int nt = 0; nt < 4; ++nt) bf_[nt] = cvt8_s(pmW1 + (size_t)(w*64 + nt*16 + ln)*385 + kc);
            #pragma unroll
            for (int mt = 0; mt < 4; ++mt)
                #pragma unroll
                for (int nt = 0; nt < 4; ++nt)
                    acc[mt][nt] = __builtin_amdgcn_mfma_f32_16x16x32_bf16(af[mt], bf_[nt], acc[mt][nt], 0, 0, 0);
        }
        #pragma unroll
        for (int mt = 0; mt < 4; ++mt)
            #pragma unroll
            for (int nt = 0; nt < 4; ++nt) {
                const int n = w*64 + nt*16 + ln;
                const float bb = pmb1[n];
                #pragma unroll
                for (int rg = 0; rg < 4; ++rg)
                    u1g[(size_t)(b0 + mt*16 + q*4 + rg)*256 + n] = acc[mt][nt][rg] + bb;
            }
    } else {
        // ---- u2 tile: u2[m0..m0+64) = query @ W1q^T (K=128), staged bf16 in LDS ----
        unsigned short* qs = (unsigned short*)smem;              // 64 x 136
        unsigned short* wsd = (unsigned short*)(smem + 17408);   // 256 x 136
        const int m0 = (bid - 141)*64;
        for (int i = tid; i < 64*128; i += 256) {
            int r = i >> 7, c = i & 127;
            qs[r*136 + c] = bf16_rne(query[(size_t)(m0 + r)*128 + c]);
        }
        for (int i = tid; i < 256*128; i += 256) {
            int n = i >> 7, c = i & 127;
            wsd[n*136 + c] = bf16_rne(pmW1[(size_t)n*385 + 256 + c]);
        }
        __syncthreads();
        f32x4 acc[4][4];
        #pragma unroll
        for (int mt = 0; mt < 4; ++mt)
            #pragma unroll
            for (int nt = 0; nt < 4; ++nt) acc[mt][nt] = (f32x4){0.f,0.f,0.f,0.f};
        #pragma unroll
        for (int kk = 0; kk < 4; ++kk) {
            const int kc = kk*32 + q*8;
            short8 af[4], bf_[4];
            #pragma unroll
            for (int mt = 0; mt < 4; ++mt) af[mt] = *(const short8*)&qs[(mt*16 + ln)*136 + kc];
            #pragma unroll
            for (int nt = 0; nt < 4; ++nt) bf_[nt] = *(const short8*)&wsd[(w*64 + nt*16 + ln)*136 + kc];
            #pragma unroll
            for (int mt = 0; mt < 4; ++mt)
                #pragma unroll
                for (int nt = 0; nt < 4; ++nt)
                    acc[mt][nt] = __builtin_amdgcn_mfma_f32_16x16x32_bf16(af[mt], bf_[nt], acc[mt][nt], 0, 0, 0);
        }
        #pragma unroll
        for (int mt = 0; mt < 4; ++mt)
            #pragma unroll
            for (int nt = 0; nt < 4; ++nt) {
                const int n = w*64 + nt*16 + ln;
                #pragma unroll
                for (int rg = 0; rg < 4; ++rg)
                    u2g[(size_t)(m0 + mt*16 + q*4 + rg)*256 + n] = acc[mt][nt][rg];
            }
    }
}

// =================== main fused kernel (identical to R5) ===================
__global__ __launch_bounds__(256, 4)
void k_main(const float* __restrict__ g,
            const float* __restrict__ invg, const float* __restrict__ ag,
            const float* __restrict__ u1g, const float* __restrict__ u2g,
            const float* __restrict__ w385g, const float* __restrict__ pmb2,
            const unsigned short* __restrict__ w2b, const unsigned short* __restrict__ wheadb,
            const float* __restrict__ bheadg, float* __restrict__ out) {
    __shared__ __align__(16) unsigned short hb[64*264];  // h1, later h2
    __shared__ __align__(16) float u1s[256], w385s[256], pmb2s[256];
    __shared__ float invs[64], gsl[192], ainv_s[64], y0s[192];

    const int tid = threadIdx.x;
    const int bid = blockIdx.x;
    const int b  = bid >> 5;
    const int m0 = (bid & 31) << 6;

    if (tid < 64)  invs[tid] = invg[b*64 + tid];
    if (tid < 192) gsl[tid]  = g[b*192 + tid];
    u1s[tid]   = u1g[b*256 + tid];
    w385s[tid] = w385g[tid];
    pmb2s[tid] = pmb2[tid];
    __syncthreads();

    // phase 1: rank-1 softmax over k; 4 threads per row
    {
        const int r = tid >> 2, sub = tid & 3;
        const float am = ag[m0 + r];
        const int kb = sub * 16;
        float mx = -1e30f;
        #pragma unroll
        for (int i = 0; i < 16; ++i) mx = fmaxf(mx, invs[kb + i] * am);
        #pragma unroll
        for (int d = 1; d < 4; d <<= 1) mx = fmaxf(mx, __shfl_xor(mx, d, 64));
        float den = 0.f, ai = 0.f, y0 = 0.f, y1 = 0.f, y2 = 0.f;
        #pragma unroll
        for (int i = 0; i < 16; ++i) {
            const int k = kb + i;
            const float iv = invs[k];
            const float e = __expf(iv * am - mx);
            den += e; ai += e * iv;
            y0 += e * gsl[k*3+0]; y1 += e * gsl[k*3+1]; y2 += e * gsl[k*3+2];
        }
        #pragma unroll
        for (int d = 1; d < 4; d <<= 1) {
            den += __shfl_xor(den, d, 64);
            ai  += __shfl_xor(ai , d, 64);
            y0  += __shfl_xor(y0 , d, 64);
            y1  += __shfl_xor(y1 , d, 64);
            y2  += __shfl_xor(y2 , d, 64);
        }
        if (sub == 0) {
            const float id = 1.0f / den;
            ainv_s[r] = ai * id;
            y0s[r*3+0] = y0*id; y0s[r*3+1] = y1*id; y0s[r*3+2] = y2*id;
        }
    }
    __syncthreads();

    // phase 1b: h1 = gelu(u2[m] + u1[b] + ainv*w385) -> bf16 LDS
    {
        const int ln16 = tid & 15, rbase = tid >> 4;
        #pragma unroll
        for (int rr = 0; rr < 4; ++rr) {
            const int r = rr*16 + rbase;
            const float aiv = ainv_s[r];
            const float* u2p = u2g + (size_t)(m0 + r)*256;
            #pragma unroll
            for (int k = 0; k < 4; ++k) {
                const int c = ln16*4 + k*64;
                float4 x  = *(const float4*)&u2p[c];
                float4 uv = *(const float4*)&u1s[c];
                float4 wv = *(const float4*)&w385s[c];
                float g0 = gelu_fast(x.x + uv.x + aiv*wv.x);
                float g1 = gelu_fast(x.y + uv.y + aiv*wv.y);
                float g2 = gelu_fast(x.z + uv.z + aiv*wv.z);
                float g3 = gelu_fast(x.w + uv.w + aiv*wv.w);
                uint2 pk; pk.x = pk_bf16(g0, g1); pk.y = pk_bf16(g2, g3);
                *(uint2*)&hb[r*264 + c] = pk;
            }
        }
    }
    __syncthreads();

    const int w = tid >> 6, lane = tid & 63;
    const int q = lane >> 4, ln = lane & 15;

    // phase 2: h2 = gelu(H1 @ W2^T + b2), 64x256x256 bf16 MFMA, 1-deep B prefetch
    f32x4 acc[4][4];
    #pragma unroll
    for (int mt = 0; mt < 4; ++mt)
        #pragma unroll
        for (int nt = 0; nt < 4; ++nt) acc[mt][nt] = (f32x4){0.f,0.f,0.f,0.f};

    {
        const unsigned short* w2p = w2b + (w*64 + ln)*256 + q*8;
        short8 bcur[4], bnxt[4];
        #pragma unroll
        for (int nt = 0; nt < 4; ++nt) bcur[nt] = *(const short8*)(w2p + nt*4096);
        #pragma unroll
        for (int kk = 0; kk < 8; ++kk) {
            if (kk < 7) {
                #pragma unroll
                for (int nt = 0; nt < 4; ++nt)
                    bnxt[nt] = *(const short8*)(w2p + nt*4096 + (kk+1)*32);
            }
            short8 afrag[4];
            const int kc = kk*32 + q*8;
            #pragma unroll
            for (int mt = 0; mt < 4; ++mt)
                afrag[mt] = *(const short8*)&hb[(mt*16 + ln)*264 + kc];
            #pragma unroll
            for (int mt = 0; mt < 4; ++mt)
                #pragma unroll
                for (int nt = 0; nt < 4; ++nt)
                    acc[mt][nt] = __builtin_amdgcn_mfma_f32_16x16x32_bf16(afrag[mt], bcur[nt], acc[mt][nt], 0, 0, 0);
            #pragma unroll
            for (int nt = 0; nt < 4; ++nt) bcur[nt] = bnxt[nt];
        }
    }
    __syncthreads();

    // h2 epilogue -> bf16 back into hb
    #pragma unroll
    for (int mt = 0; mt < 4; ++mt) {
        #pragma unroll
        for (int nt = 0; nt < 4; ++nt) {
            const int n = w*64 + nt*16 + ln;
            const float bb = pmb2s[n];
            const int r0 = mt*16 + q*4;
            float h0 = gelu_fast(acc[mt][nt][0] + bb);
            float h1 = gelu_fast(acc[mt][nt][1] + bb);
            float h2 = gelu_fast(acc[mt][nt][2] + bb);
            float h3 = gelu_fast(acc[mt][nt][3] + bb);
            unsigned p01 = pk_bf16(h0, h1);
            unsigned p23 = pk_bf16(h2, h3);
            hb[(r0+0)*264 + n] = (unsigned short)(p01 & 0xFFFF);
            hb[(r0+1)*264 + n] = (unsigned short)(p01 >> 16);
            hb[(r0+2)*264 + n] = (unsigned short)(p23 & 0xFFFF);
            hb[(r0+3)*264 + n] = (unsigned short)(p23 >> 16);
        }
    }

    // preload phase-3 A frags before the barrier (vmcnt drain = prefetch)
    const int cb2 = (ln < 2) ? (32 + ln) : 33;
    const unsigned short* whp = wheadb + q*8;
    short8 wf0 = *(const short8*)(whp +  ln      *256);
    short8 wf1 = *(const short8*)(whp + (16 + ln)*256);
    short8 wf2 = *(const short8*)(whp +  cb2     *256);
    __syncthreads();

    // phase 3: heads
    f32x4 accA0 = {0.f,0.f,0.f,0.f}, accA1 = {0.f,0.f,0.f,0.f}, accB = {0.f,0.f,0.f,0.f};
    const int rr = w*16 + ln;
    #pragma unroll
    for (int kk = 0; kk < 8; ++kk) {
        short8 wn0, wn1, wn2;
        if (kk < 7) {
            wn0 = *(const short8*)(whp +  ln      *256 + (kk+1)*32);
            wn1 = *(const short8*)(whp + (16 + ln)*256 + (kk+1)*32);
            wn2 = *(const short8*)(whp +  cb2     *256 + (kk+1)*32);
        }
        short8 bh = *(const short8*)&hb[rr*264 + kk*32 + q*8];
        accA0 = __builtin_amdgcn_mfma_f32_16x16x32_bf16(wf0, bh, accA0, 0, 0, 0);
        accA1 = __builtin_amdgcn_mfma_f32_16x16x32_bf16(wf1, bh, accA1, 0, 0, 0);
        accB  = __builtin_amdgcn_mfma_f32_16x16x32_bf16(wf2, bh, accB , 0, 0, 0);
        wf0 = wn0; wf1 = wn1; wf2 = wn2;
    }
    {
        const size_t row = (size_t)b*2048 + m0 + rr;
        const int c0 = q*4;
        f32x4 r0 = accA0 + *(const f32x4*)&bheadg[c0];
        f32x4 r1 = accA1 + *(const f32x4*)&bheadg[16 + c0];
        *(f32x4*)&out[786432 + row*32 + c0]      = r0;
        *(f32x4*)&out[786432 + row*32 + 16 + c0] = r1;
        if (q == 0) {
            out[9175040 + row] = accB[0] + bheadg[32];
            float gv = accB[1] + bheadg[33];
            float gt = 1.0f / (1.0f + __expf(-gv));
            gt = fminf(fmaxf(gt, 0.0f), 1.0f);
            float* yo = out + row*3;
            yo[0] = y0s[rr*3+0] * gt;
            yo[1] = y0s[rr*3+1] * gt;
            yo[2] = y0s[rr*3+2] * gt;
        }
    }
}

// ---------------- launcher ----------------
extern "C" void kernel_launch(void* const* d_in, const int* in_sizes, int n_in,
                              void* d_out, int out_size, void* d_ws, size_t ws_size,
                              hipStream_t stream) {
    const float* g     = (const float*)d_in[0];
    const float* query = (const float*)d_in[1];
    const float* qW    = (const float*)d_in[2];
    const float* qb    = (const float*)d_in[3];
    const float* kW    = (const float*)d_in[4];
    // d_in[5] = kb (cancels in softmax)
    const float* gmW1  = (const float*)d_in[6];
    const float* gmb1  = (const float*)d_in[7];
    const float* gmW2  = (const float*)d_in[8];
    const float* gmb2  = (const float*)d_in[9];
    const float* gmW3  = (const float*)d_in[10];
    const float* gmb3  = (const float*)d_in[11];
    const float* pmW1  = (const float*)d_in[12];
    const float* pmb1  = (const float*)d_in[13];
    const float* pmW2  = (const float*)d_in[14];
    const float* pmb2  = (const float*)d_in[15];
    const float* pmW3  = (const float*)d_in[16];
    const float* pmb3  = (const float*)d_in[17];
    const float* tW    = (const float*)d_in[18];
    const float* tb    = (const float*)d_in[19];
    const float* wW    = (const float*)d_in[20];
    const float* wb    = (const float*)d_in[21];
    const float* cW    = (const float*)d_in[22];
    const float* cb    = (const float*)d_in[23];
    float* out = (float*)d_out;

    // workspace layout (float slots)
    float* ws    = (float*)d_ws;
    float* invg  = ws;                                       // 8192 -> 8192
    float* ag    = ws + 8192;                                // 2048 -> 10240
    float* u1g   = ws + 10240;                               // 32768 -> 43008
    float* w385g = ws + 43008;                               // 256 -> 43264
    float* bheadg= ws + 43264;                               // 64 -> 43328
    unsigned short* w2b    = (unsigned short*)(ws + 43328);  // 65536 sh -> 76096
    unsigned short* wheadb = (unsigned short*)(ws + 76096);  // 8704 sh -> 80448
    float* u2g   = ws + 80448;                               // 524288 -> 604736 (~2.4 MB)

    hipLaunchKernelGGL(k_prep, dim3(173), dim3(256), 0, stream,
                       g, qW, qb, kW, query, pmW1, pmb1, pmW2, pmW3, pmb3,
                       gmW1, gmb1, gmW2, gmb2, gmW3, gmb3,
                       tW, tb, wW, wb, cW, cb,
                       invg, ag, u1g, u2g, w2b, wheadb, bheadg, w385g);
    hipLaunchKernelGGL(k_main, dim3(4096), dim3(256), 0, stream,
                       g, invg, ag, u1g, u2g, w385g, pmb2,
                       w2b, wheadb, bheadg, out);
}